// Round 9
// baseline (213.255 us; speedup 1.0000x reference)
//
#include <hip/hip_runtime.h>
#include <hip/hip_bf16.h>

typedef unsigned short u16;
typedef __bf16 bf16x8 __attribute__((ext_vector_type(8)));
typedef float f32x4 __attribute__((ext_vector_type(4)));
typedef unsigned short u16x8 __attribute__((ext_vector_type(8)));
typedef unsigned short u16x4 __attribute__((ext_vector_type(4)));

__device__ __forceinline__ float bf2f(u16 u) {
  unsigned x = ((unsigned)u) << 16;
  return __builtin_bit_cast(float, x);
}
__device__ __forceinline__ u16 f2bf(float f) {
  unsigned u = __builtin_bit_cast(unsigned, f);
  u += 0x7fffu + ((u >> 16) & 1u);
  return (u16)(u >> 16);
}

// async global -> LDS, 16B per lane; lds base wave-uniform, HW scatters base+lane*16.
__device__ __forceinline__ void gload16(const u16* g, u16* lds) {
  __builtin_amdgcn_global_load_lds(
      (const __attribute__((address_space(1))) void*)g,
      (__attribute__((address_space(3))) void*)lds,
      16, 0, 0);
}

// Unpinned sync (R7): compiler memory fences only, no sched_barrier(0).
__device__ __forceinline__ void bar() {
  asm volatile("" ::: "memory");
  __builtin_amdgcn_s_barrier();
  asm volatile("" ::: "memory");
}
template <int N> __device__ __forceinline__ void wait_vm() {
  asm volatile("s_waitcnt vmcnt(%0)" :: "n"(N) : "memory");
}
__device__ __forceinline__ void wait_lgkm0() {
  asm volatile("s_waitcnt lgkmcnt(0)" ::: "memory");
}

// =========================================================================
// 256x256 bf16 GEMM, 4-phase, ONE barrier per K-tile (R9; R8 had 2, gave
// +12% over 8 -> continue the validated lever).
// Schedule per tile s (d = s&1):
//   p0: ds (d,0) mh0+B          -> MFMA acc[0..3]   (compiler lgkm waits)
//   p1: ds (d,0) mh1            -> MFMA acc[4..7]
//   p2: ds (d,1) mh0+B          -> MFMA acc[0..3]
//   p3: ds (d,1) mh1; lgkm0 (cross-wave: ALL my tile-s reads retired);
//       vmcnt(0) (retires tile s+1's 8 loads, issued a full tile ago ->
//       long landed, drain is free); BAR (the one barrier);
//       stage tile s+2 FULLY (8 gloads into (d,0)+(d,1), both freed by
//       this bar); MFMA acc[4..7].
// Safety: bar at p3 requires every wave's p0-p3 reads retired (per-wave
// lgkm0 + common bar) -> staging over both families is race-free; skew
// bounded to one tile; staged data consumed only after the NEXT tile's
// p3 vmcnt -> landed before its readers.  Per-phase explicit lgkm0 drains
// removed: own-wave ds->MFMA deps are compiler-tracked (fine-grained
// lgkmcnt(N)); only p3's full drain is load-bearing (cross-wave).
// Tail: tiles NT-2, NT-1 don't stage.  Prologue: tiles 0+1 (16 loads),
// vmcnt(8) retires tile 0.
// C[M,N] = A[M,K] * B[N,K]^T * cscale.  OUT_MODE: 1 = bf16 out, 0 = f32 out.
// 512 threads = 8 waves (2M x 4N); per-wave out 128x64 = 8x4 frags 16x16.
// LDS 128KB: A[d][h] @ (d*2+h)*8192, B[d][h] @ 32768 + (d*2+h)*8192 (u16),
// d = tile&1.  Swizzle: slot = row*4 + (q ^ ((row^(row>>2))&3)); staging
// pre-swizzles the per-lane GLOBAL source so the linear gload scatter lands.
// =========================================================================
#define OFF_A(d,h) (((d)*2+(h))*8192)
#define OFF_B(d,h) (32768 + ((d)*2+(h))*8192)

struct G256 {
  const u16 *gA0, *gA1, *gB0, *gB1;  // per-lane staging src (k=0)
  int dst0, dst1;                    // LDS elem offsets within a unit
  int aoff0[4], aoff1[4], boff[4];   // frag LDS elem offsets within (d,h) region
  u16* lds;
};

__device__ __forceinline__ int swz_slot(int row, int q) {
  return row * 4 + (q ^ ((row ^ (row >> 2)) & 3));
}

__device__ __forceinline__ void mfma_quad(f32x4 (*accr)[4], const bf16x8* af, const bf16x8* bf) {
#pragma unroll
  for (int i = 0; i < 4; ++i)
#pragma unroll
    for (int j = 0; j < 4; ++j)
      accr[i][j] = __builtin_amdgcn_mfma_f32_16x16x32_bf16(af[i], bf[j], accr[i][j], 0, 0, 0);
}

template <bool STG>
__device__ __forceinline__ void ktile256(const G256& g, int s, f32x4 (&acc)[8][4]) {
  const int d = s & 1;
  bf16x8 af[4], bf[4];
  const int kt2 = (s + 2) * 64;        // tile staged this iteration

  // ---- phase 0: khalf0, mhalf0 ----
#pragma unroll
  for (int i = 0; i < 4; ++i) af[i] = *(const bf16x8*)(g.lds + OFF_A(d, 0) + g.aoff0[i]);
#pragma unroll
  for (int j = 0; j < 4; ++j) bf[j] = *(const bf16x8*)(g.lds + OFF_B(d, 0) + g.boff[j]);
  __builtin_amdgcn_s_setprio(1);
  mfma_quad(&acc[0], af, bf);
  __builtin_amdgcn_s_setprio(0);

  // ---- phase 1: khalf0, mhalf1 (reuse bf) ----
#pragma unroll
  for (int i = 0; i < 4; ++i) af[i] = *(const bf16x8*)(g.lds + OFF_A(d, 0) + g.aoff1[i]);
  __builtin_amdgcn_s_setprio(1);
  mfma_quad(&acc[4], af, bf);
  __builtin_amdgcn_s_setprio(0);

  // ---- phase 2: khalf1, mhalf0 ----
#pragma unroll
  for (int i = 0; i < 4; ++i) af[i] = *(const bf16x8*)(g.lds + OFF_A(d, 1) + g.aoff0[i]);
#pragma unroll
  for (int j = 0; j < 4; ++j) bf[j] = *(const bf16x8*)(g.lds + OFF_B(d, 1) + g.boff[j]);
  __builtin_amdgcn_s_setprio(1);
  mfma_quad(&acc[0], af, bf);
  __builtin_amdgcn_s_setprio(0);

  // ---- phase 3: khalf1, mhalf1; the one lgkm0/vmcnt/barrier; stage s+2 ----
#pragma unroll
  for (int i = 0; i < 4; ++i) af[i] = *(const bf16x8*)(g.lds + OFF_A(d, 1) + g.aoff1[i]);
  wait_lgkm0();                        // my tile-s reads all retired
  wait_vm<0>();                        // tile s+1's loads (issued 1 tile ago) in
  bar();                               // publish both; (d,0)+(d,1) now free
  if (STG) {
    gload16(g.gA0 + kt2,      g.lds + OFF_A(d, 0) + g.dst0);
    gload16(g.gA1 + kt2,      g.lds + OFF_A(d, 0) + g.dst1);
    gload16(g.gA0 + kt2 + 32, g.lds + OFF_A(d, 1) + g.dst0);
    gload16(g.gA1 + kt2 + 32, g.lds + OFF_A(d, 1) + g.dst1);
    gload16(g.gB0 + kt2,      g.lds + OFF_B(d, 0) + g.dst0);
    gload16(g.gB1 + kt2,      g.lds + OFF_B(d, 0) + g.dst1);
    gload16(g.gB0 + kt2 + 32, g.lds + OFF_B(d, 1) + g.dst0);
    gload16(g.gB1 + kt2 + 32, g.lds + OFF_B(d, 1) + g.dst1);
  }
  __builtin_amdgcn_s_setprio(1);
  mfma_quad(&acc[4], af, bf);
  __builtin_amdgcn_s_setprio(0);
}

template <int OUT_MODE, int NX, int NT>
__device__ __forceinline__ void gemm256_body(
    const u16* __restrict__ A, int lda, const u16* __restrict__ B, int ldb,
    void* __restrict__ C, int ldc, float cscale, u16* lds, int bid)
{
  static_assert(NT >= 3, "tail peel needs NT>=3");
  const int by = (bid & 7) + 8 * (bid / (8 * NX));
  const int bx = (bid >> 3) % NX;
  const int m0 = by * 256, n0 = bx * 256;
  const int t = threadIdx.x;
  const int w = t >> 6, l = t & 63;
  const int wm = (w >> 2) * 128, wn = (w & 3) * 64;
  const int fr = l & 15, q = l >> 4;

  G256 g;
  g.lds = lds;
  // staging lane constants: unit slot = w*64 + l
  {
    const int s0 = w * 64 + l;
    const int r0 = s0 >> 2, r1 = r0 + 128;
    const int q0 = (s0 & 3) ^ ((r0 ^ (r0 >> 2)) & 3);
    const int q1 = (s0 & 3) ^ ((r1 ^ (r1 >> 2)) & 3);
    g.gA0 = A + (size_t)(m0 + r0) * lda + q0 * 8;
    g.gA1 = A + (size_t)(m0 + r1) * lda + q1 * 8;
    g.gB0 = B + (size_t)(n0 + r0) * ldb + q0 * 8;
    g.gB1 = B + (size_t)(n0 + r1) * ldb + q1 * 8;
    g.dst0 = (w * 64) * 8;
    g.dst1 = (512 + w * 64) * 8;
  }
  // fragment lane constants
#pragma unroll
  for (int i = 0; i < 4; ++i) {
    g.aoff0[i] = swz_slot(wm + 16 * i + fr, q) * 8;
    g.aoff1[i] = swz_slot(wm + 64 + 16 * i + fr, q) * 8;
    g.boff[i]  = swz_slot(wn + 16 * i + fr, q) * 8;
  }

  f32x4 acc[8][4] = {};

  // prologue: tiles 0 and 1 fully (16 loads); vmcnt(8) retires tile 0
#pragma unroll
  for (int s = 0; s < 2; ++s) {
    const int kt = s * 64, d = s & 1;
    gload16(g.gA0 + kt,      lds + OFF_A(d, 0) + g.dst0);
    gload16(g.gA1 + kt,      lds + OFF_A(d, 0) + g.dst1);
    gload16(g.gA0 + kt + 32, lds + OFF_A(d, 1) + g.dst0);
    gload16(g.gA1 + kt + 32, lds + OFF_A(d, 1) + g.dst1);
    gload16(g.gB0 + kt,      lds + OFF_B(d, 0) + g.dst0);
    gload16(g.gB1 + kt,      lds + OFF_B(d, 0) + g.dst1);
    gload16(g.gB0 + kt + 32, lds + OFF_B(d, 1) + g.dst0);
    gload16(g.gB1 + kt + 32, lds + OFF_B(d, 1) + g.dst1);
  }
  wait_vm<8>();
  bar();

  for (int s = 0; s + 2 < NT; ++s)
    ktile256<true>(g, s, acc);
  ktile256<false>(g, NT - 2, acc);
  ktile256<false>(g, NT - 1, acc);

  // ---- epilogue: per-wave LDS round-trip, coalesced 16B stores ----
  // C/D layout (m89): col = lane&15, row = (lane>>4)*4 + reg
  bar();                               // all main-loop LDS reads retired
  const int er = q * 4, ec = fr;
  const int rg = l >> 3, c = l & 7;

  if (OUT_MODE == 1) {
    u16* Ch = (u16*)C;
    u16* eb = lds + w * 4608;              // 64 rows x 72 u16 per wave
#pragma unroll
    for (int half = 0; half < 2; ++half) {
#pragma unroll
      for (int i = 0; i < 4; ++i)
#pragma unroll
        for (int j = 0; j < 4; ++j)
#pragma unroll
          for (int r = 0; r < 4; ++r)
            eb[(16 * i + er + r) * 72 + 16 * j + ec] = f2bf(acc[4 * half + i][j][r] * cscale);
#pragma unroll
      for (int k = 0; k < 8; ++k) {
        const int row = k * 8 + rg;
        u16x8 v = *(const u16x8*)(eb + row * 72 + c * 8);
        *(u16x8*)(Ch + (size_t)(m0 + wm + 64 * half + row) * ldc + n0 + wn + c * 8) = v;
      }
    }
  } else {
    float* Cf = (float*)C;
    float* eb = (float*)lds + w * 2304;    // 32 rows x 72 f32 (9216B) per wave
#pragma unroll
    for (int half = 0; half < 2; ++half)
#pragma unroll
      for (int ip = 0; ip < 2; ++ip) {
#pragma unroll
        for (int ii = 0; ii < 2; ++ii)
#pragma unroll
          for (int j = 0; j < 4; ++j)
#pragma unroll
            for (int r = 0; r < 4; ++r)
              eb[(16 * ii + er + r) * 72 + 16 * j + ec] = acc[4 * half + 2 * ip + ii][j][r] * cscale;
#pragma unroll
        for (int k = 0; k < 4; ++k) {
          const int row = k * 8 + rg;
          float4 v0 = *(const float4*)(eb + row * 72 + c * 4);
          float4 v1 = *(const float4*)(eb + row * 72 + (c + 8) * 4);
          float* dst = Cf + (size_t)(m0 + wm + 64 * half + 32 * ip + row) * ldc + n0 + wn;
          *(float4*)(dst + c * 4) = v0;
          *(float4*)(dst + (c + 8) * 4) = v1;
        }
      }
  }
}

// stage 1: QKV = E @ Wt^T  [4096 x 3072], K=1024.  grid 192 (16x12).
__global__ __launch_bounds__(512, 2) void gemm_qkv256(const u16* __restrict__ A,
                                                      const u16* __restrict__ B,
                                                      u16* __restrict__ C) {
  __shared__ __align__(16) u16 lds[65536];   // 128 KiB
  gemm256_body<1, 12, 16>(A, 1024, B, 1024, C, 3072, 1.0f, lds, blockIdx.x);
}

// stage 2: S = (Q @ K^T)/32  [4096 x 4096], K=1024.  grid 256 (16x16).
__global__ __launch_bounds__(512, 2) void gemm_score256(const u16* __restrict__ QKV,
                                                        u16* __restrict__ S) {
  __shared__ __align__(16) u16 lds[65536];
  gemm256_body<1, 16, 16>(QKV, 3072, QKV + 1024, 3072, S, 4096, 0.03125f, lds, blockIdx.x);
}

// -------------------------------------------------------------------------
// stage 4: Out = P @ Vt^T  [4096 x 1024], K=4096 — split-K x4.
// 64 tiles x 4 splits = 256 blocks; per-block 256x256xK=1024 (== score).
// f32 partials (ws >= 146MB, confirmed running) or bf16 fallback.
// -------------------------------------------------------------------------
__global__ __launch_bounds__(512, 2) void gemm_pv256f(const u16* __restrict__ S,
                                                      const u16* __restrict__ Vt,
                                                      float* __restrict__ P4) {
  __shared__ __align__(16) u16 lds[65536];
  const int b = blockIdx.x;
  const int sp = b >> 6;                    // 0..3 K-split
  float* Cp = P4 + (size_t)sp * 4096 * 1024;
  gemm256_body<0, 4, 16>(S + sp * 1024, 4096, Vt + sp * 1024, 4096,
                         Cp, 1024, 1.0f, lds, b & 63);
}

__global__ __launch_bounds__(512, 2) void gemm_pv256h(const u16* __restrict__ S,
                                                      const u16* __restrict__ Vt,
                                                      u16* __restrict__ P4) {
  __shared__ __align__(16) u16 lds[65536];
  const int b = blockIdx.x;
  const int sp = b >> 6;
  u16* Cp = P4 + (size_t)sp * 4096 * 1024;
  gemm256_body<1, 4, 16>(S + sp * 1024, 4096, Vt + sp * 1024, 4096,
                         Cp, 1024, 1.0f, lds, b & 63);
}

// stage 5: Out = sum of 4 partials.  16B/thread out.
__global__ __launch_bounds__(256) void reduce4f(const float* __restrict__ P4,
                                                float* __restrict__ O) {
  const size_t i = ((size_t)blockIdx.x * 256 + threadIdx.x) * 4;
  const size_t st = (size_t)4096 * 1024;
  float4 a = *(const float4*)(P4 + i);
  float4 b = *(const float4*)(P4 + st + i);
  float4 c = *(const float4*)(P4 + 2 * st + i);
  float4 d = *(const float4*)(P4 + 3 * st + i);
  float4 o;
  o.x = (a.x + b.x) + (c.x + d.x);
  o.y = (a.y + b.y) + (c.y + d.y);
  o.z = (a.z + b.z) + (c.z + d.z);
  o.w = (a.w + b.w) + (c.w + d.w);
  *(float4*)(O + i) = o;
}

__global__ __launch_bounds__(256) void reduce4h(const u16* __restrict__ P4,
                                                float* __restrict__ O) {
  const size_t i = ((size_t)blockIdx.x * 256 + threadIdx.x) * 4;
  const size_t st = (size_t)4096 * 1024;
  u16x4 a = *(const u16x4*)(P4 + i);
  u16x4 b = *(const u16x4*)(P4 + st + i);
  u16x4 c = *(const u16x4*)(P4 + 2 * st + i);
  u16x4 d = *(const u16x4*)(P4 + 3 * st + i);
  float4 o;
  o.x = (bf2f(a.x) + bf2f(b.x)) + (bf2f(c.x) + bf2f(d.x));
  o.y = (bf2f(a.y) + bf2f(b.y)) + (bf2f(c.y) + bf2f(d.y));
  o.z = (bf2f(a.z) + bf2f(b.z)) + (bf2f(c.z) + bf2f(d.z));
  o.w = (bf2f(a.w) + bf2f(b.w)) + (bf2f(c.w) + bf2f(d.w));
  *(float4*)(O + i) = o;
}

// -------------------------------------------------------------------------
// stage 0 merged: blocks 0..4095 = E f32->bf16 cast; 4096..7167 = W transposes.
// -------------------------------------------------------------------------
__global__ __launch_bounds__(256) void prep(
    const float* __restrict__ E,
    const float* __restrict__ w0, const float* __restrict__ w1,
    const float* __restrict__ w2,
    u16* __restrict__ Ebf, u16* __restrict__ Wt)
{
  int b = blockIdx.x;
  if (b < 4096) {
    const int i = (b * 256 + threadIdx.x) * 4;
    float4 f = *(const float4*)(E + i);
    u16x4 o;
    o.x = f2bf(f.x); o.y = f2bf(f.y); o.z = f2bf(f.z); o.w = f2bf(f.w);
    *(u16x4*)(Ebf + i) = o;
  } else {
    b -= 4096;
    const int which = b >> 10;
    const int tile = b & 1023;
    const float* in = (which == 0) ? w0 : (which == 1) ? w1 : w2;
    u16* o = Wt + (size_t)which * 1024 * 1024;
    const int c0 = (tile & 31) * 32, r0 = (tile >> 5) * 32;
    __shared__ u16 tl[32][33];
    const int tx = threadIdx.x & 31, ty0 = threadIdx.x >> 5;
#pragma unroll
    for (int k = 0; k < 4; ++k) {
      const int ty = ty0 + k * 8;
      tl[ty][tx] = f2bf(in[(size_t)(r0 + ty) * 1024 + c0 + tx]);
    }
    __syncthreads();
#pragma unroll
    for (int k = 0; k < 4; ++k) {
      const int ty = ty0 + k * 8;
      o[(size_t)(c0 + ty) * 1024 + r0 + tx] = tl[tx][ty];
    }
  }
}

// -------------------------------------------------------------------------
// stage 3 merged: blocks 0..4095 = row softmax (in-place, bf16 S, scale
// pre-applied); blocks 4096..8191 = V transpose (32x32 tiles).
// -------------------------------------------------------------------------
__global__ __launch_bounds__(256) void softmax_tv(u16* __restrict__ S,
                                                  const u16* __restrict__ QKV,
                                                  u16* __restrict__ Vt) {
  __shared__ float red[8];
  __shared__ u16 tl[32][33];
  const int b = blockIdx.x;
  if (b < 4096) {
    const int N = 4096;
    u16* p = S + (size_t)b * N;
    const int t = threadIdx.x;
    u16x8 u0 = ((const u16x8*)p)[t * 2];
    u16x8 u1 = ((const u16x8*)p)[t * 2 + 1];
    float v[16];
#pragma unroll
    for (int i = 0; i < 8; ++i) v[i] = bf2f(u0[i]);
#pragma unroll
    for (int i = 0; i < 8; ++i) v[8 + i] = bf2f(u1[i]);

    float m = -1e30f;
#pragma unroll
    for (int i = 0; i < 16; ++i) m = fmaxf(m, v[i]);
#pragma unroll
    for (int off = 32; off; off >>= 1) m = fmaxf(m, __shfl_xor(m, off));
    if ((t & 63) == 0) red[t >> 6] = m;
    __syncthreads();
    m = fmaxf(fmaxf(red[0], red[1]), fmaxf(red[2], red[3]));

    float s = 0.f;
#pragma unroll
    for (int i = 0; i < 16; ++i) { v[i] = __expf(v[i] - m); s += v[i]; }
#pragma unroll
    for (int off = 32; off; off >>= 1) s += __shfl_xor(s, off);
    if ((t & 63) == 0) red[4 + (t >> 6)] = s;
    __syncthreads();
    s = (red[4] + red[5]) + (red[6] + red[7]);
    const float inv = 1.0f / s;

    u16x8 o0, o1;
#pragma unroll
    for (int i = 0; i < 8; ++i) o0[i] = f2bf(v[i] * inv);
#pragma unroll
    for (int i = 0; i < 8; ++i) o1[i] = f2bf(v[8 + i] * inv);
    ((u16x8*)p)[t * 2] = o0;
    ((u16x8*)p)[t * 2 + 1] = o1;
  } else {
    const int v = b - 4096;                       // 0..4095
    const int c0 = (v & 31) * 32;                 // V col 0..1023
    const int r0 = (v >> 5) * 32;                 // V row 0..4095
    const int tx = threadIdx.x & 31, ty0 = threadIdx.x >> 5;
    const u16* Vin = QKV + 2048;                  // V cols of QKV (ld 3072)
#pragma unroll
    for (int k = 0; k < 4; ++k) {
      const int ty = ty0 + k * 8;
      tl[ty][tx] = Vin[(size_t)(r0 + ty) * 3072 + c0 + tx];
    }
    __syncthreads();
#pragma unroll
    for (int k = 0; k < 4; ++k) {
      const int ty = ty0 + k * 8;
      Vt[(size_t)(c0 + ty) * 4096 + r0 + tx] = tl[tx][ty];
    }
  }
}

// -------------------------------------------------------------------------
// S=4096, D_IN=1024, D_OUT=1024.  fp32 in, fp32 out.
// ws (bytes): Ebf 0-8M | Wt 8-14M | QKV 14-38M | Vt 38-46M | S 46-78M.
// PV partials: f32 64MB @78M if ws >= 146MB, else bf16 32MB @0.
// 6 dispatches: prep -> qkv -> score -> softmax+tV -> pv-splitK -> reduce.
// All GEMMs: 256² 4-phase body, 1 barrier/K-tile (R9).
// -------------------------------------------------------------------------
extern "C" void kernel_launch(void* const* d_in, const int* in_sizes, int n_in,
                              void* d_out, int out_size, void* d_ws, size_t ws_size,
                              hipStream_t stream) {
  const float* E  = (const float*)d_in[0];
  const float* Wq = (const float*)d_in[1];
  const float* Wk = (const float*)d_in[2];
  const float* Wv = (const float*)d_in[3];
  float* Out = (float*)d_out;

  char* w = (char*)d_ws;
  u16* Ebf = (u16*)(w);
  u16* Wt  = (u16*)(w + (size_t)(8u << 20));
  u16* QKV = (u16*)(w + (size_t)(14u << 20));
  u16* Vt  = (u16*)(w + (size_t)(38u << 20));
  u16* S   = (u16*)(w + (size_t)(46u << 20));

  // stage 0: E cast + W transposes
  prep<<<7168, 256, 0, stream>>>(E, Wq, Wk, Wv, Ebf, Wt);

  // stage 1: QKV = E @ Wt^T   [4096 x 3072], K=1024
  gemm_qkv256<<<192, 512, 0, stream>>>(Ebf, Wt, QKV);

  // stage 2: S = (Q @ K^T) / 32
  gemm_score256<<<256, 512, 0, stream>>>(QKV, S);

  // stage 3: P = softmax(S) in place  +  V^T
  softmax_tv<<<8192, 256, 0, stream>>>(S, QKV, Vt);

  // stage 4+5: Out = P @ Vt^T via split-K x4 + reduce
  if (ws_size >= ((size_t)146u << 20)) {
    float* P4 = (float*)(w + ((size_t)78u << 20));
    gemm_pv256f<<<256, 512, 0, stream>>>(S, Vt, P4);
    reduce4f<<<4096, 256, 0, stream>>>(P4, Out);
  } else {
    u16* P4 = (u16*)w;                    // aliases dead Ebf/Wt/QKV
    gemm_pv256h<<<256, 512, 0, stream>>>(S, Vt, P4);
    reduce4h<<<4096, 256, 0, stream>>>(P4, Out);
  }
}

// Round 10
// 202.106 us; speedup vs baseline: 1.0552x; 1.0552x over previous
//
#include <hip/hip_runtime.h>
#include <hip/hip_bf16.h>

typedef unsigned short u16;
typedef __bf16 bf16x8 __attribute__((ext_vector_type(8)));
typedef float f32x4 __attribute__((ext_vector_type(4)));
typedef unsigned short u16x8 __attribute__((ext_vector_type(8)));
typedef unsigned short u16x4 __attribute__((ext_vector_type(4)));

__device__ __forceinline__ float bf2f(u16 u) {
  unsigned x = ((unsigned)u) << 16;
  return __builtin_bit_cast(float, x);
}
__device__ __forceinline__ u16 f2bf(float f) {
  unsigned u = __builtin_bit_cast(unsigned, f);
  u += 0x7fffu + ((u >> 16) & 1u);
  return (u16)(u >> 16);
}

// async global -> LDS, 16B per lane; lds base wave-uniform, HW scatters base+lane*16.
__device__ __forceinline__ void gload16(const u16* g, u16* lds) {
  __builtin_amdgcn_global_load_lds(
      (const __attribute__((address_space(1))) void*)g,
      (__attribute__((address_space(3))) void*)lds,
      16, 0, 0);
}

// Unpinned sync (R7): compiler memory fences only, no sched_barrier(0).
__device__ __forceinline__ void bar() {
  asm volatile("" ::: "memory");
  __builtin_amdgcn_s_barrier();
  asm volatile("" ::: "memory");
}
template <int N> __device__ __forceinline__ void wait_vm() {
  asm volatile("s_waitcnt vmcnt(%0)" :: "n"(N) : "memory");
}
__device__ __forceinline__ void wait_lgkm0() {
  asm volatile("s_waitcnt lgkmcnt(0)" ::: "memory");
}

// =========================================================================
// 256x256 bf16 GEMM, 4-phase, TWO barriers per K-tile — the R8 body,
// the best-measured variant (pv 41.0us @ 31.9% MfmaUtil; R9's 1-barrier
// + vmcnt(0) drain regressed to 43.6 -> reverted).
// Barriers (load-bearing only):
//   BAR@p1 (after p1 lgkm0): all waves' reads of (d,0) retired -> p2 may
//     re-stage (d,0) with (s+2,h0).
//   BAR@p3 (after p3 lgkm0 + counted vmcnt<4>): all waves' reads of (d,1)
//     retired -> next tile's p0 may re-stage; vmcnt<4> retires ALL of tile
//     s+1's units (counted, never 0 mid-loop).
// Load-order induction (unit = 2 gload16):
//   prologue (0,A0)(0,B0)(0,A1)(0,B1)(1,A0)(1,B0)=12, wait<4> -> tile0 in.
//   tile s: p0 stages (s+1,A1)(s+1,B1), p2 stages (s+2,A0)(s+2,B0);
//   at p3 outstanding=12, wait<4> retires 8 oldest = all of tile s+1. ✓
// C[M,N] = A[M,K] * B[N,K]^T * cscale.  OUT_MODE: 1 = bf16 out, 0 = f32 out.
// 512 threads = 8 waves (2M x 4N); per-wave out 128x64 = 8x4 frags 16x16.
// LDS 128KB: A[d][h] @ (d*2+h)*8192, B[d][h] @ 32768 + (d*2+h)*8192 (u16),
// d = tile&1.  Swizzle: slot = row*4 + (q ^ ((row^(row>>2))&3)); staging
// pre-swizzles the per-lane GLOBAL source so the linear gload scatter lands.
// =========================================================================
#define OFF_A(d,h) (((d)*2+(h))*8192)
#define OFF_B(d,h) (32768 + ((d)*2+(h))*8192)

struct G256 {
  const u16 *gA0, *gA1, *gB0, *gB1;  // per-lane staging src (k=0)
  int dst0, dst1;                    // LDS elem offsets within a unit
  int aoff0[4], aoff1[4], boff[4];   // frag LDS elem offsets within (d,h) region
  u16* lds;
};

__device__ __forceinline__ int swz_slot(int row, int q) {
  return row * 4 + (q ^ ((row ^ (row >> 2)) & 3));
}

__device__ __forceinline__ void mfma_quad(f32x4 (*accr)[4], const bf16x8* af, const bf16x8* bf) {
#pragma unroll
  for (int i = 0; i < 4; ++i)
#pragma unroll
    for (int j = 0; j < 4; ++j)
      accr[i][j] = __builtin_amdgcn_mfma_f32_16x16x32_bf16(af[i], bf[j], accr[i][j], 0, 0, 0);
}

template <int W3, bool S01, bool S23>
__device__ __forceinline__ void ktile256(const G256& g, int s, f32x4 (&acc)[8][4]) {
  const int d = s & 1;
  bf16x8 af[4], bf[4];
  const int kA1 = (s + 1) * 64 + 32;   // next tile, k-half 1
  const int kA0 = (s + 2) * 64;        // tile after next, k-half 0

  // ---- phase 0: khalf0, mhalf0; stage (s+1, h1); NO barrier ----
#pragma unroll
  for (int i = 0; i < 4; ++i) af[i] = *(const bf16x8*)(g.lds + OFF_A(d, 0) + g.aoff0[i]);
#pragma unroll
  for (int j = 0; j < 4; ++j) bf[j] = *(const bf16x8*)(g.lds + OFF_B(d, 0) + g.boff[j]);
  if (S01) {
    gload16(g.gA0 + kA1, g.lds + OFF_A(d ^ 1, 1) + g.dst0);
    gload16(g.gA1 + kA1, g.lds + OFF_A(d ^ 1, 1) + g.dst1);
    gload16(g.gB0 + kA1, g.lds + OFF_B(d ^ 1, 1) + g.dst0);
    gload16(g.gB1 + kA1, g.lds + OFF_B(d ^ 1, 1) + g.dst1);
  }
  wait_lgkm0();
  __builtin_amdgcn_s_setprio(1);
  mfma_quad(&acc[0], af, bf);
  __builtin_amdgcn_s_setprio(0);

  // ---- phase 1: khalf0, mhalf1 (reuse bf); BAR after reads retire ----
#pragma unroll
  for (int i = 0; i < 4; ++i) af[i] = *(const bf16x8*)(g.lds + OFF_A(d, 0) + g.aoff1[i]);
  wait_lgkm0();
  bar();                               // publishes: (d,0) free for re-stage
  __builtin_amdgcn_s_setprio(1);
  mfma_quad(&acc[4], af, bf);
  __builtin_amdgcn_s_setprio(0);

  // ---- phase 2: khalf1, mhalf0; stage (s+2, h0) into (d,0); NO barrier ----
#pragma unroll
  for (int i = 0; i < 4; ++i) af[i] = *(const bf16x8*)(g.lds + OFF_A(d, 1) + g.aoff0[i]);
#pragma unroll
  for (int j = 0; j < 4; ++j) bf[j] = *(const bf16x8*)(g.lds + OFF_B(d, 1) + g.boff[j]);
  if (S23) {
    gload16(g.gA0 + kA0, g.lds + OFF_A(d, 0) + g.dst0);
    gload16(g.gA1 + kA0, g.lds + OFF_A(d, 0) + g.dst1);
    gload16(g.gB0 + kA0, g.lds + OFF_B(d, 0) + g.dst0);
    gload16(g.gB1 + kA0, g.lds + OFF_B(d, 0) + g.dst1);
  }
  wait_lgkm0();
  __builtin_amdgcn_s_setprio(1);
  mfma_quad(&acc[0], af, bf);
  __builtin_amdgcn_s_setprio(0);

  // ---- phase 3: khalf1, mhalf1; the one counted vmcnt; BAR ----
#pragma unroll
  for (int i = 0; i < 4; ++i) af[i] = *(const bf16x8*)(g.lds + OFF_A(d, 1) + g.aoff1[i]);
  wait_lgkm0();
  if constexpr (W3 >= 0) wait_vm<(W3 >= 0 ? W3 : 0)>();
  bar();                               // publishes: (d,1) free; tile s+1 landed
  __builtin_amdgcn_s_setprio(1);
  mfma_quad(&acc[4], af, bf);
  __builtin_amdgcn_s_setprio(0);
}

template <int OUT_MODE, int NX, int NT>
__device__ __forceinline__ void gemm256_body(
    const u16* __restrict__ A, int lda, const u16* __restrict__ B, int ldb,
    void* __restrict__ C, int ldc, float cscale, u16* lds, int bid)
{
  static_assert(NT >= 3, "tail peel needs NT>=3");
  const int by = (bid & 7) + 8 * (bid / (8 * NX));
  const int bx = (bid >> 3) % NX;
  const int m0 = by * 256, n0 = bx * 256;
  const int t = threadIdx.x;
  const int w = t >> 6, l = t & 63;
  const int wm = (w >> 2) * 128, wn = (w & 3) * 64;
  const int fr = l & 15, q = l >> 4;

  G256 g;
  g.lds = lds;
  // staging lane constants: unit slot = w*64 + l
  {
    const int s0 = w * 64 + l;
    const int r0 = s0 >> 2, r1 = r0 + 128;
    const int q0 = (s0 & 3) ^ ((r0 ^ (r0 >> 2)) & 3);
    const int q1 = (s0 & 3) ^ ((r1 ^ (r1 >> 2)) & 3);
    g.gA0 = A + (size_t)(m0 + r0) * lda + q0 * 8;
    g.gA1 = A + (size_t)(m0 + r1) * lda + q1 * 8;
    g.gB0 = B + (size_t)(n0 + r0) * ldb + q0 * 8;
    g.gB1 = B + (size_t)(n0 + r1) * ldb + q1 * 8;
    g.dst0 = (w * 64) * 8;
    g.dst1 = (512 + w * 64) * 8;
  }
  // fragment lane constants
#pragma unroll
  for (int i = 0; i < 4; ++i) {
    g.aoff0[i] = swz_slot(wm + 16 * i + fr, q) * 8;
    g.aoff1[i] = swz_slot(wm + 64 + 16 * i + fr, q) * 8;
    g.boff[i]  = swz_slot(wn + 16 * i + fr, q) * 8;
  }

  f32x4 acc[8][4] = {};

  // prologue: (0,A0)(0,B0)(0,A1)(0,B1)(1,A0)(1,B0); wait retires tile0
  gload16(g.gA0 + 0,  lds + OFF_A(0, 0) + g.dst0);
  gload16(g.gA1 + 0,  lds + OFF_A(0, 0) + g.dst1);
  gload16(g.gB0 + 0,  lds + OFF_B(0, 0) + g.dst0);
  gload16(g.gB1 + 0,  lds + OFF_B(0, 0) + g.dst1);
  gload16(g.gA0 + 32, lds + OFF_A(0, 1) + g.dst0);
  gload16(g.gA1 + 32, lds + OFF_A(0, 1) + g.dst1);
  gload16(g.gB0 + 32, lds + OFF_B(0, 1) + g.dst0);
  gload16(g.gB1 + 32, lds + OFF_B(0, 1) + g.dst1);
  gload16(g.gA0 + 64, lds + OFF_A(1, 0) + g.dst0);
  gload16(g.gA1 + 64, lds + OFF_A(1, 0) + g.dst1);
  gload16(g.gB0 + 64, lds + OFF_B(1, 0) + g.dst0);
  gload16(g.gB1 + 64, lds + OFF_B(1, 0) + g.dst1);
  wait_vm<4>();
  bar();

  for (int s = 0; s + 2 < NT; ++s)
    ktile256<4, true, true>(g, s, acc);
  ktile256<0, true, false>(g, NT - 2, acc);
  ktile256<-1, false, false>(g, NT - 1, acc);

  // ---- epilogue: per-wave LDS round-trip, coalesced 16B stores ----
  // C/D layout (m89): col = lane&15, row = (lane>>4)*4 + reg
  bar();                               // all main-loop LDS reads retired
  const int er = q * 4, ec = fr;
  const int rg = l >> 3, c = l & 7;

  if (OUT_MODE == 1) {
    u16* Ch = (u16*)C;
    u16* eb = lds + w * 4608;              // 64 rows x 72 u16 per wave
#pragma unroll
    for (int half = 0; half < 2; ++half) {
#pragma unroll
      for (int i = 0; i < 4; ++i)
#pragma unroll
        for (int j = 0; j < 4; ++j)
#pragma unroll
          for (int r = 0; r < 4; ++r)
            eb[(16 * i + er + r) * 72 + 16 * j + ec] = f2bf(acc[4 * half + i][j][r] * cscale);
#pragma unroll
      for (int k = 0; k < 8; ++k) {
        const int row = k * 8 + rg;
        u16x8 v = *(const u16x8*)(eb + row * 72 + c * 8);
        *(u16x8*)(Ch + (size_t)(m0 + wm + 64 * half + row) * ldc + n0 + wn + c * 8) = v;
      }
    }
  } else {
    float* Cf = (float*)C;
    float* eb = (float*)lds + w * 2304;    // 32 rows x 72 f32 (9216B) per wave
#pragma unroll
    for (int half = 0; half < 2; ++half)
#pragma unroll
      for (int ip = 0; ip < 2; ++ip) {
#pragma unroll
        for (int ii = 0; ii < 2; ++ii)
#pragma unroll
          for (int j = 0; j < 4; ++j)
#pragma unroll
            for (int r = 0; r < 4; ++r)
              eb[(16 * ii + er + r) * 72 + 16 * j + ec] = acc[4 * half + 2 * ip + ii][j][r] * cscale;
#pragma unroll
        for (int k = 0; k < 4; ++k) {
          const int row = k * 8 + rg;
          float4 v0 = *(const float4*)(eb + row * 72 + c * 4);
          float4 v1 = *(const float4*)(eb + row * 72 + (c + 8) * 4);
          float* dst = Cf + (size_t)(m0 + wm + 64 * half + 32 * ip + row) * ldc + n0 + wn;
          *(float4*)(dst + c * 4) = v0;
          *(float4*)(dst + (c + 8) * 4) = v1;
        }
      }
  }
}

// stage 1: QKV = E @ Wt^T  [4096 x 3072], K=1024.  grid 192 (16x12).
__global__ __launch_bounds__(512, 2) void gemm_qkv256(const u16* __restrict__ A,
                                                      const u16* __restrict__ B,
                                                      u16* __restrict__ C) {
  __shared__ __align__(16) u16 lds[65536];   // 128 KiB
  gemm256_body<1, 12, 16>(A, 1024, B, 1024, C, 3072, 1.0f, lds, blockIdx.x);
}

// stage 2: S = (Q @ K^T)/32  [4096 x 4096], K=1024.  grid 256 (16x16).
__global__ __launch_bounds__(512, 2) void gemm_score256(const u16* __restrict__ QKV,
                                                        u16* __restrict__ S) {
  __shared__ __align__(16) u16 lds[65536];
  gemm256_body<1, 16, 16>(QKV, 3072, QKV + 1024, 3072, S, 4096, 0.03125f, lds, blockIdx.x);
}

// -------------------------------------------------------------------------
// stage 4: Out = P @ Vt^T  [4096 x 1024], K=4096 — split-K x4, R8 body,
// BF16 partials (R10): halves pv write traffic (64->32MB) and reduce read
// traffic.  Error budget: partial magnitudes ~0.01-0.05, bf16 rel round
// 2^-9 -> <=1e-4 added absmax (below the 2.44e-4 bf16-P noise floor).
// 64 tiles x 4 splits = 256 blocks; per-block 256x256xK=1024 (== score).
// -------------------------------------------------------------------------
__global__ __launch_bounds__(512, 2) void gemm_pv256h(const u16* __restrict__ S,
                                                      const u16* __restrict__ Vt,
                                                      u16* __restrict__ P4) {
  __shared__ __align__(16) u16 lds[65536];
  const int b = blockIdx.x;
  const int sp = b >> 6;                    // 0..3 K-split
  u16* Cp = P4 + (size_t)sp * 4096 * 1024;
  gemm256_body<1, 4, 16>(S + sp * 1024, 4096, Vt + sp * 1024, 4096,
                         Cp, 1024, 1.0f, lds, b & 63);
}

// stage 5: Out = sum of 4 bf16 partials.  8 outputs/thread, 16B loads.
__global__ __launch_bounds__(256) void reduce4h(const u16* __restrict__ P4,
                                                float* __restrict__ O) {
  const size_t i = ((size_t)blockIdx.x * 256 + threadIdx.x) * 8;
  const size_t st = (size_t)4096 * 1024;
  u16x8 a = *(const u16x8*)(P4 + i);
  u16x8 b = *(const u16x8*)(P4 + st + i);
  u16x8 c = *(const u16x8*)(P4 + 2 * st + i);
  u16x8 d = *(const u16x8*)(P4 + 3 * st + i);
  float4 o0, o1;
#pragma unroll
  for (int j = 0; j < 4; ++j) {
    (&o0.x)[j] = (bf2f(a[j]) + bf2f(b[j])) + (bf2f(c[j]) + bf2f(d[j]));
    (&o1.x)[j] = (bf2f(a[4 + j]) + bf2f(b[4 + j])) + (bf2f(c[4 + j]) + bf2f(d[4 + j]));
  }
  *(float4*)(O + i) = o0;
  *(float4*)(O + i + 4) = o1;
}

// -------------------------------------------------------------------------
// stage 0 merged: blocks 0..4095 = E f32->bf16 cast; 4096..7167 = W transposes.
// -------------------------------------------------------------------------
__global__ __launch_bounds__(256) void prep(
    const float* __restrict__ E,
    const float* __restrict__ w0, const float* __restrict__ w1,
    const float* __restrict__ w2,
    u16* __restrict__ Ebf, u16* __restrict__ Wt)
{
  int b = blockIdx.x;
  if (b < 4096) {
    const int i = (b * 256 + threadIdx.x) * 4;
    float4 f = *(const float4*)(E + i);
    u16x4 o;
    o.x = f2bf(f.x); o.y = f2bf(f.y); o.z = f2bf(f.z); o.w = f2bf(f.w);
    *(u16x4*)(Ebf + i) = o;
  } else {
    b -= 4096;
    const int which = b >> 10;
    const int tile = b & 1023;
    const float* in = (which == 0) ? w0 : (which == 1) ? w1 : w2;
    u16* o = Wt + (size_t)which * 1024 * 1024;
    const int c0 = (tile & 31) * 32, r0 = (tile >> 5) * 32;
    __shared__ u16 tl[32][33];
    const int tx = threadIdx.x & 31, ty0 = threadIdx.x >> 5;
#pragma unroll
    for (int k = 0; k < 4; ++k) {
      const int ty = ty0 + k * 8;
      tl[ty][tx] = f2bf(in[(size_t)(r0 + ty) * 1024 + c0 + tx]);
    }
    __syncthreads();
#pragma unroll
    for (int k = 0; k < 4; ++k) {
      const int ty = ty0 + k * 8;
      o[(size_t)(c0 + ty) * 1024 + r0 + tx] = tl[tx][ty];
    }
  }
}

// -------------------------------------------------------------------------
// stage 3 merged: blocks 0..4095 = row softmax (in-place, bf16 S, scale
// pre-applied); blocks 4096..8191 = V transpose (32x32 tiles).
// -------------------------------------------------------------------------
__global__ __launch_bounds__(256) void softmax_tv(u16* __restrict__ S,
                                                  const u16* __restrict__ QKV,
                                                  u16* __restrict__ Vt) {
  __shared__ float red[8];
  __shared__ u16 tl[32][33];
  const int b = blockIdx.x;
  if (b < 4096) {
    const int N = 4096;
    u16* p = S + (size_t)b * N;
    const int t = threadIdx.x;
    u16x8 u0 = ((const u16x8*)p)[t * 2];
    u16x8 u1 = ((const u16x8*)p)[t * 2 + 1];
    float v[16];
#pragma unroll
    for (int i = 0; i < 8; ++i) v[i] = bf2f(u0[i]);
#pragma unroll
    for (int i = 0; i < 8; ++i) v[8 + i] = bf2f(u1[i]);

    float m = -1e30f;
#pragma unroll
    for (int i = 0; i < 16; ++i) m = fmaxf(m, v[i]);
#pragma unroll
    for (int off = 32; off; off >>= 1) m = fmaxf(m, __shfl_xor(m, off));
    if ((t & 63) == 0) red[t >> 6] = m;
    __syncthreads();
    m = fmaxf(fmaxf(red[0], red[1]), fmaxf(red[2], red[3]));

    float s = 0.f;
#pragma unroll
    for (int i = 0; i < 16; ++i) { v[i] = __expf(v[i] - m); s += v[i]; }
#pragma unroll
    for (int off = 32; off; off >>= 1) s += __shfl_xor(s, off);
    if ((t & 63) == 0) red[4 + (t >> 6)] = s;
    __syncthreads();
    s = (red[4] + red[5]) + (red[6] + red[7]);
    const float inv = 1.0f / s;

    u16x8 o0, o1;
#pragma unroll
    for (int i = 0; i < 8; ++i) o0[i] = f2bf(v[i] * inv);
#pragma unroll
    for (int i = 0; i < 8; ++i) o1[i] = f2bf(v[8 + i] * inv);
    ((u16x8*)p)[t * 2] = o0;
    ((u16x8*)p)[t * 2 + 1] = o1;
  } else {
    const int v = b - 4096;                       // 0..4095
    const int c0 = (v & 31) * 32;                 // V col 0..1023
    const int r0 = (v >> 5) * 32;                 // V row 0..4095
    const int tx = threadIdx.x & 31, ty0 = threadIdx.x >> 5;
    const u16* Vin = QKV + 2048;                  // V cols of QKV (ld 3072)
#pragma unroll
    for (int k = 0; k < 4; ++k) {
      const int ty = ty0 + k * 8;
      tl[ty][tx] = Vin[(size_t)(r0 + ty) * 3072 + c0 + tx];
    }
    __syncthreads();
#pragma unroll
    for (int k = 0; k < 4; ++k) {
      const int ty = ty0 + k * 8;
      Vt[(size_t)(c0 + ty) * 4096 + r0 + tx] = tl[tx][ty];
    }
  }
}

// -------------------------------------------------------------------------
// S=4096, D_IN=1024, D_OUT=1024.  fp32 in, fp32 out.
// ws (bytes): Ebf 0-8M | Wt 8-14M | QKV 14-38M | Vt 38-46M | S 46-78M |
// P4 (bf16 partials, 32MB) @78M if ws >= 110MB, else aliases dead 0-32M.
// 6 dispatches: prep -> qkv -> score -> softmax+tV -> pv-splitK -> reduce.
// All GEMMs: 256² 4-phase R8 body (2 barriers/K-tile, counted vmcnt(4)).
// -------------------------------------------------------------------------
extern "C" void kernel_launch(void* const* d_in, const int* in_sizes, int n_in,
                              void* d_out, int out_size, void* d_ws, size_t ws_size,
                              hipStream_t stream) {
  const float* E  = (const float*)d_in[0];
  const float* Wq = (const float*)d_in[1];
  const float* Wk = (const float*)d_in[2];
  const float* Wv = (const float*)d_in[3];
  float* Out = (float*)d_out;

  char* w = (char*)d_ws;
  u16* Ebf = (u16*)(w);
  u16* Wt  = (u16*)(w + (size_t)(8u << 20));
  u16* QKV = (u16*)(w + (size_t)(14u << 20));
  u16* Vt  = (u16*)(w + (size_t)(38u << 20));
  u16* S   = (u16*)(w + (size_t)(46u << 20));
  u16* P4  = (ws_size >= ((size_t)110u << 20)) ? (u16*)(w + (size_t)(78u << 20))
                                               : (u16*)w;  // dead Ebf/Wt/QKV

  // stage 0: E cast + W transposes
  prep<<<7168, 256, 0, stream>>>(E, Wq, Wk, Wv, Ebf, Wt);

  // stage 1: QKV = E @ Wt^T   [4096 x 3072], K=1024
  gemm_qkv256<<<192, 512, 0, stream>>>(Ebf, Wt, QKV);

  // stage 2: S = (Q @ K^T) / 32
  gemm_score256<<<256, 512, 0, stream>>>(QKV, S);

  // stage 3: P = softmax(S) in place  +  V^T
  softmax_tv<<<8192, 256, 0, stream>>>(S, QKV, Vt);

  // stage 4+5: Out = P @ Vt^T via split-K x4 (bf16 partials) + reduce
  gemm_pv256h<<<256, 512, 0, stream>>>(S, Vt, P4);
  reduce4h<<<2048, 256, 0, stream>>>(P4, Out);
}

// Round 11
// 198.780 us; speedup vs baseline: 1.0728x; 1.0167x over previous
//
#include <hip/hip_runtime.h>
#include <hip/hip_bf16.h>

typedef unsigned short u16;
typedef __bf16 bf16x8 __attribute__((ext_vector_type(8)));
typedef float f32x4 __attribute__((ext_vector_type(4)));
typedef unsigned short u16x8 __attribute__((ext_vector_type(8)));
typedef unsigned short u16x4 __attribute__((ext_vector_type(4)));

__device__ __forceinline__ float bf2f(u16 u) {
  unsigned x = ((unsigned)u) << 16;
  return __builtin_bit_cast(float, x);
}
__device__ __forceinline__ u16 f2bf(float f) {
  unsigned u = __builtin_bit_cast(unsigned, f);
  u += 0x7fffu + ((u >> 16) & 1u);
  return (u16)(u >> 16);
}

// async global -> LDS, 16B per lane; lds base wave-uniform, HW scatters base+lane*16.
__device__ __forceinline__ void gload16(const u16* g, u16* lds) {
  __builtin_amdgcn_global_load_lds(
      (const __attribute__((address_space(1))) void*)g,
      (__attribute__((address_space(3))) void*)lds,
      16, 0, 0);
}

// Unpinned sync (R7): compiler memory fences only, no sched_barrier(0).
__device__ __forceinline__ void bar() {
  asm volatile("" ::: "memory");
  __builtin_amdgcn_s_barrier();
  asm volatile("" ::: "memory");
}
template <int N> __device__ __forceinline__ void wait_vm() {
  asm volatile("s_waitcnt vmcnt(%0)" :: "n"(N) : "memory");
}
__device__ __forceinline__ void wait_lgkm0() {
  asm volatile("s_waitcnt lgkmcnt(0)" ::: "memory");
}

// =========================================================================
// 256x256 bf16 GEMM, 4-phase, TWO barriers per K-tile — the R8 body
// (best-measured: pv 41.0us @ 31.9% MfmaUtil; R9's 1-barrier vmcnt(0)
// drain regressed -> reverted; R10 added bf16 split-K partials, 202.1us).
// Barriers (load-bearing only):
//   BAR@p1 (after p1 lgkm0): all waves' reads of (d,0) retired -> p2 may
//     re-stage (d,0) with (s+2,h0).
//   BAR@p3 (after p3 lgkm0 + counted vmcnt<4>): all waves' reads of (d,1)
//     retired -> next tile's p0 may re-stage; vmcnt<4> retires ALL of tile
//     s+1's units (counted, never 0 mid-loop).
// Load-order induction (unit = 2 gload16):
//   prologue (0,A0)(0,B0)(0,A1)(0,B1)(1,A0)(1,B0)=12, wait<4> -> tile0 in.
//   tile s: p0 stages (s+1,A1)(s+1,B1), p2 stages (s+2,A0)(s+2,B0);
//   at p3 outstanding=12, wait<4> retires 8 oldest = all of tile s+1. ✓
// OUT_MODE: 1 = bf16 out; 0 = f32 out; 2 = bf16 TRANSPOSED out (R11: V
// tiles of qkv write Vt[n0-2048+col][m] directly — same LDS round-trip,
// indices swapped on the scalar acc->eb writes (2-way bank alias, free
// m136), identical coalesced u16x8 store pattern; kills the separate
// V-transpose pass and 24MB of HBM traffic.  Values bit-identical.
// 512 threads = 8 waves (2M x 4N); per-wave out 128x64 = 8x4 frags 16x16.
// LDS 128KB: A[d][h] @ (d*2+h)*8192, B[d][h] @ 32768 + (d*2+h)*8192 (u16),
// d = tile&1.  Swizzle: slot = row*4 + (q ^ ((row^(row>>2))&3)); staging
// pre-swizzles the per-lane GLOBAL source so the linear gload scatter lands.
// =========================================================================
#define OFF_A(d,h) (((d)*2+(h))*8192)
#define OFF_B(d,h) (32768 + ((d)*2+(h))*8192)

struct G256 {
  const u16 *gA0, *gA1, *gB0, *gB1;  // per-lane staging src (k=0)
  int dst0, dst1;                    // LDS elem offsets within a unit
  int aoff0[4], aoff1[4], boff[4];   // frag LDS elem offsets within (d,h) region
  u16* lds;
};

__device__ __forceinline__ int swz_slot(int row, int q) {
  return row * 4 + (q ^ ((row ^ (row >> 2)) & 3));
}

__device__ __forceinline__ void mfma_quad(f32x4 (*accr)[4], const bf16x8* af, const bf16x8* bf) {
#pragma unroll
  for (int i = 0; i < 4; ++i)
#pragma unroll
    for (int j = 0; j < 4; ++j)
      accr[i][j] = __builtin_amdgcn_mfma_f32_16x16x32_bf16(af[i], bf[j], accr[i][j], 0, 0, 0);
}

template <int W3, bool S01, bool S23>
__device__ __forceinline__ void ktile256(const G256& g, int s, f32x4 (&acc)[8][4]) {
  const int d = s & 1;
  bf16x8 af[4], bf[4];
  const int kA1 = (s + 1) * 64 + 32;   // next tile, k-half 1
  const int kA0 = (s + 2) * 64;        // tile after next, k-half 0

  // ---- phase 0: khalf0, mhalf0; stage (s+1, h1); NO barrier ----
#pragma unroll
  for (int i = 0; i < 4; ++i) af[i] = *(const bf16x8*)(g.lds + OFF_A(d, 0) + g.aoff0[i]);
#pragma unroll
  for (int j = 0; j < 4; ++j) bf[j] = *(const bf16x8*)(g.lds + OFF_B(d, 0) + g.boff[j]);
  if (S01) {
    gload16(g.gA0 + kA1, g.lds + OFF_A(d ^ 1, 1) + g.dst0);
    gload16(g.gA1 + kA1, g.lds + OFF_A(d ^ 1, 1) + g.dst1);
    gload16(g.gB0 + kA1, g.lds + OFF_B(d ^ 1, 1) + g.dst0);
    gload16(g.gB1 + kA1, g.lds + OFF_B(d ^ 1, 1) + g.dst1);
  }
  wait_lgkm0();
  __builtin_amdgcn_s_setprio(1);
  mfma_quad(&acc[0], af, bf);
  __builtin_amdgcn_s_setprio(0);

  // ---- phase 1: khalf0, mhalf1 (reuse bf); BAR after reads retire ----
#pragma unroll
  for (int i = 0; i < 4; ++i) af[i] = *(const bf16x8*)(g.lds + OFF_A(d, 0) + g.aoff1[i]);
  wait_lgkm0();
  bar();                               // publishes: (d,0) free for re-stage
  __builtin_amdgcn_s_setprio(1);
  mfma_quad(&acc[4], af, bf);
  __builtin_amdgcn_s_setprio(0);

  // ---- phase 2: khalf1, mhalf0; stage (s+2, h0) into (d,0); NO barrier ----
#pragma unroll
  for (int i = 0; i < 4; ++i) af[i] = *(const bf16x8*)(g.lds + OFF_A(d, 1) + g.aoff0[i]);
#pragma unroll
  for (int j = 0; j < 4; ++j) bf[j] = *(const bf16x8*)(g.lds + OFF_B(d, 1) + g.boff[j]);
  if (S23) {
    gload16(g.gA0 + kA0, g.lds + OFF_A(d, 0) + g.dst0);
    gload16(g.gA1 + kA0, g.lds + OFF_A(d, 0) + g.dst1);
    gload16(g.gB0 + kA0, g.lds + OFF_B(d, 0) + g.dst0);
    gload16(g.gB1 + kA0, g.lds + OFF_B(d, 0) + g.dst1);
  }
  wait_lgkm0();
  __builtin_amdgcn_s_setprio(1);
  mfma_quad(&acc[0], af, bf);
  __builtin_amdgcn_s_setprio(0);

  // ---- phase 3: khalf1, mhalf1; the one counted vmcnt; BAR ----
#pragma unroll
  for (int i = 0; i < 4; ++i) af[i] = *(const bf16x8*)(g.lds + OFF_A(d, 1) + g.aoff1[i]);
  wait_lgkm0();
  if constexpr (W3 >= 0) wait_vm<(W3 >= 0 ? W3 : 0)>();
  bar();                               // publishes: (d,1) free; tile s+1 landed
  __builtin_amdgcn_s_setprio(1);
  mfma_quad(&acc[4], af, bf);
  __builtin_amdgcn_s_setprio(0);
}

template <int OUT_MODE, int NX, int NT>
__device__ __forceinline__ void gemm256_body(
    const u16* __restrict__ A, int lda, const u16* __restrict__ B, int ldb,
    void* __restrict__ C, int ldc, float cscale, u16* lds, int bid)
{
  static_assert(NT >= 3, "tail peel needs NT>=3");
  const int by = (bid & 7) + 8 * (bid / (8 * NX));
  const int bx = (bid >> 3) % NX;
  const int m0 = by * 256, n0 = bx * 256;
  const int t = threadIdx.x;
  const int w = t >> 6, l = t & 63;
  const int wm = (w >> 2) * 128, wn = (w & 3) * 64;
  const int fr = l & 15, q = l >> 4;

  G256 g;
  g.lds = lds;
  // staging lane constants: unit slot = w*64 + l
  {
    const int s0 = w * 64 + l;
    const int r0 = s0 >> 2, r1 = r0 + 128;
    const int q0 = (s0 & 3) ^ ((r0 ^ (r0 >> 2)) & 3);
    const int q1 = (s0 & 3) ^ ((r1 ^ (r1 >> 2)) & 3);
    g.gA0 = A + (size_t)(m0 + r0) * lda + q0 * 8;
    g.gA1 = A + (size_t)(m0 + r1) * lda + q1 * 8;
    g.gB0 = B + (size_t)(n0 + r0) * ldb + q0 * 8;
    g.gB1 = B + (size_t)(n0 + r1) * ldb + q1 * 8;
    g.dst0 = (w * 64) * 8;
    g.dst1 = (512 + w * 64) * 8;
  }
  // fragment lane constants
#pragma unroll
  for (int i = 0; i < 4; ++i) {
    g.aoff0[i] = swz_slot(wm + 16 * i + fr, q) * 8;
    g.aoff1[i] = swz_slot(wm + 64 + 16 * i + fr, q) * 8;
    g.boff[i]  = swz_slot(wn + 16 * i + fr, q) * 8;
  }

  f32x4 acc[8][4] = {};

  // prologue: (0,A0)(0,B0)(0,A1)(0,B1)(1,A0)(1,B0); wait retires tile0
  gload16(g.gA0 + 0,  lds + OFF_A(0, 0) + g.dst0);
  gload16(g.gA1 + 0,  lds + OFF_A(0, 0) + g.dst1);
  gload16(g.gB0 + 0,  lds + OFF_B(0, 0) + g.dst0);
  gload16(g.gB1 + 0,  lds + OFF_B(0, 0) + g.dst1);
  gload16(g.gA0 + 32, lds + OFF_A(0, 1) + g.dst0);
  gload16(g.gA1 + 32, lds + OFF_A(0, 1) + g.dst1);
  gload16(g.gB0 + 32, lds + OFF_B(0, 1) + g.dst0);
  gload16(g.gB1 + 32, lds + OFF_B(0, 1) + g.dst1);
  gload16(g.gA0 + 64, lds + OFF_A(1, 0) + g.dst0);
  gload16(g.gA1 + 64, lds + OFF_A(1, 0) + g.dst1);
  gload16(g.gB0 + 64, lds + OFF_B(1, 0) + g.dst0);
  gload16(g.gB1 + 64, lds + OFF_B(1, 0) + g.dst1);
  wait_vm<4>();
  bar();

  for (int s = 0; s + 2 < NT; ++s)
    ktile256<4, true, true>(g, s, acc);
  ktile256<0, true, false>(g, NT - 2, acc);
  ktile256<-1, false, false>(g, NT - 1, acc);

  // ---- epilogue: per-wave LDS round-trip, coalesced 16B stores ----
  // C/D layout (m89): col = lane&15, row = (lane>>4)*4 + reg
  bar();                               // all main-loop LDS reads retired
  const int er = q * 4, ec = fr;
  const int rg = l >> 3, c = l & 7;

  if (OUT_MODE == 1) {
    u16* Ch = (u16*)C;
    u16* eb = lds + w * 4608;              // 64 rows x 72 u16 per wave
#pragma unroll
    for (int half = 0; half < 2; ++half) {
#pragma unroll
      for (int i = 0; i < 4; ++i)
#pragma unroll
        for (int j = 0; j < 4; ++j)
#pragma unroll
          for (int r = 0; r < 4; ++r)
            eb[(16 * i + er + r) * 72 + 16 * j + ec] = f2bf(acc[4 * half + i][j][r] * cscale);
#pragma unroll
      for (int k = 0; k < 8; ++k) {
        const int row = k * 8 + rg;
        u16x8 v = *(const u16x8*)(eb + row * 72 + c * 8);
        *(u16x8*)(Ch + (size_t)(m0 + wm + 64 * half + row) * ldc + n0 + wn + c * 8) = v;
      }
    }
  } else if (OUT_MODE == 2) {
    // transposed bf16: C = Vt (ld = ldc); Vt[n0-2048+col][m] = tile[m][col].
    // eb indices swapped on the scalar writes: eb[col*72 + mrow].
    u16* Ch = (u16*)C;
    const int n0v = n0 - 2048;
    u16* eb = lds + w * 4608;
#pragma unroll
    for (int half = 0; half < 2; ++half) {
#pragma unroll
      for (int i = 0; i < 4; ++i)
#pragma unroll
        for (int j = 0; j < 4; ++j)
#pragma unroll
          for (int r = 0; r < 4; ++r)
            eb[(16 * j + ec) * 72 + 16 * i + er + r] = f2bf(acc[4 * half + i][j][r] * cscale);
#pragma unroll
      for (int k = 0; k < 8; ++k) {
        const int row = k * 8 + rg;           // = col within wn block
        u16x8 v = *(const u16x8*)(eb + row * 72 + c * 8);
        *(u16x8*)(Ch + (size_t)(n0v + wn + row) * ldc + m0 + wm + 64 * half + c * 8) = v;
      }
    }
  } else {
    float* Cf = (float*)C;
    float* eb = (float*)lds + w * 2304;    // 32 rows x 72 f32 (9216B) per wave
#pragma unroll
    for (int half = 0; half < 2; ++half)
#pragma unroll
      for (int ip = 0; ip < 2; ++ip) {
#pragma unroll
        for (int ii = 0; ii < 2; ++ii)
#pragma unroll
          for (int j = 0; j < 4; ++j)
#pragma unroll
            for (int r = 0; r < 4; ++r)
              eb[(16 * ii + er + r) * 72 + 16 * j + ec] = acc[4 * half + 2 * ip + ii][j][r] * cscale;
#pragma unroll
        for (int k = 0; k < 4; ++k) {
          const int row = k * 8 + rg;
          float4 v0 = *(const float4*)(eb + row * 72 + c * 4);
          float4 v1 = *(const float4*)(eb + row * 72 + (c + 8) * 4);
          float* dst = Cf + (size_t)(m0 + wm + 64 * half + 32 * ip + row) * ldc + n0 + wn;
          *(float4*)(dst + c * 4) = v0;
          *(float4*)(dst + (c + 8) * 4) = v1;
        }
      }
  }
}

// stage 1: QKV = E @ Wt^T  [4096 x 3072], K=1024.  grid 192 (16x12).
// Q,K tiles (bx<8) -> QKV (bf16); V tiles (bx>=8) -> Vt TRANSPOSED (R11),
// eliminating the separate V-transpose pass + 24MB HBM traffic.
__global__ __launch_bounds__(512, 2) void gemm_qkv256(const u16* __restrict__ A,
                                                      const u16* __restrict__ B,
                                                      u16* __restrict__ C,
                                                      u16* __restrict__ Vt) {
  __shared__ __align__(16) u16 lds[65536];   // 128 KiB
  const int bid = blockIdx.x;
  const int bx = (bid >> 3) % 12;
  if (bx < 8)
    gemm256_body<1, 12, 16>(A, 1024, B, 1024, C, 3072, 1.0f, lds, bid);
  else
    gemm256_body<2, 12, 16>(A, 1024, B, 1024, Vt, 4096, 1.0f, lds, bid);
}

// stage 2: S = (Q @ K^T)/32  [4096 x 4096], K=1024.  grid 256 (16x16).
__global__ __launch_bounds__(512, 2) void gemm_score256(const u16* __restrict__ QKV,
                                                        u16* __restrict__ S) {
  __shared__ __align__(16) u16 lds[65536];
  gemm256_body<1, 16, 16>(QKV, 3072, QKV + 1024, 3072, S, 4096, 0.03125f, lds, blockIdx.x);
}

// -------------------------------------------------------------------------
// stage 4: Out = P @ Vt^T  [4096 x 1024], K=4096 — split-K x4, R8 body,
// bf16 partials (R10-validated: absmax unchanged, -6.5us).
// 64 tiles x 4 splits = 256 blocks; per-block 256x256xK=1024 (== score).
// -------------------------------------------------------------------------
__global__ __launch_bounds__(512, 2) void gemm_pv256h(const u16* __restrict__ S,
                                                      const u16* __restrict__ Vt,
                                                      u16* __restrict__ P4) {
  __shared__ __align__(16) u16 lds[65536];
  const int b = blockIdx.x;
  const int sp = b >> 6;                    // 0..3 K-split
  u16* Cp = P4 + (size_t)sp * 4096 * 1024;
  gemm256_body<1, 4, 16>(S + sp * 1024, 4096, Vt + sp * 1024, 4096,
                         Cp, 1024, 1.0f, lds, b & 63);
}

// stage 5: Out = sum of 4 bf16 partials.  8 outputs/thread, 16B loads.
__global__ __launch_bounds__(256) void reduce4h(const u16* __restrict__ P4,
                                                float* __restrict__ O) {
  const size_t i = ((size_t)blockIdx.x * 256 + threadIdx.x) * 8;
  const size_t st = (size_t)4096 * 1024;
  u16x8 a = *(const u16x8*)(P4 + i);
  u16x8 b = *(const u16x8*)(P4 + st + i);
  u16x8 c = *(const u16x8*)(P4 + 2 * st + i);
  u16x8 d = *(const u16x8*)(P4 + 3 * st + i);
  float4 o0, o1;
#pragma unroll
  for (int j = 0; j < 4; ++j) {
    (&o0.x)[j] = (bf2f(a[j]) + bf2f(b[j])) + (bf2f(c[j]) + bf2f(d[j]));
    (&o1.x)[j] = (bf2f(a[4 + j]) + bf2f(b[4 + j])) + (bf2f(c[4 + j]) + bf2f(d[4 + j]));
  }
  *(float4*)(O + i) = o0;
  *(float4*)(O + i + 4) = o1;
}

// -------------------------------------------------------------------------
// stage 0 merged: blocks 0..4095 = E f32->bf16 cast; 4096..7167 = W transposes.
// -------------------------------------------------------------------------
__global__ __launch_bounds__(256) void prep(
    const float* __restrict__ E,
    const float* __restrict__ w0, const float* __restrict__ w1,
    const float* __restrict__ w2,
    u16* __restrict__ Ebf, u16* __restrict__ Wt)
{
  int b = blockIdx.x;
  if (b < 4096) {
    const int i = (b * 256 + threadIdx.x) * 4;
    float4 f = *(const float4*)(E + i);
    u16x4 o;
    o.x = f2bf(f.x); o.y = f2bf(f.y); o.z = f2bf(f.z); o.w = f2bf(f.w);
    *(u16x4*)(Ebf + i) = o;
  } else {
    b -= 4096;
    const int which = b >> 10;
    const int tile = b & 1023;
    const float* in = (which == 0) ? w0 : (which == 1) ? w1 : w2;
    u16* o = Wt + (size_t)which * 1024 * 1024;
    const int c0 = (tile & 31) * 32, r0 = (tile >> 5) * 32;
    __shared__ u16 tl[32][33];
    const int tx = threadIdx.x & 31, ty0 = threadIdx.x >> 5;
#pragma unroll
    for (int k = 0; k < 4; ++k) {
      const int ty = ty0 + k * 8;
      tl[ty][tx] = f2bf(in[(size_t)(r0 + ty) * 1024 + c0 + tx]);
    }
    __syncthreads();
#pragma unroll
    for (int k = 0; k < 4; ++k) {
      const int ty = ty0 + k * 8;
      o[(size_t)(c0 + ty) * 1024 + r0 + tx] = tl[tx][ty];
    }
  }
}

// -------------------------------------------------------------------------
// stage 3: row softmax, in-place on bf16 S[4096][4096] (scale pre-applied).
// (V-transpose removed — handled by qkv's transposed epilogue, R11.)
// -------------------------------------------------------------------------
__global__ __launch_bounds__(256) void softmax_rows(u16* __restrict__ S) {
  const int N = 4096;
  u16* p = S + (size_t)blockIdx.x * N;
  const int t = threadIdx.x;
  u16x8 u0 = ((const u16x8*)p)[t * 2];
  u16x8 u1 = ((const u16x8*)p)[t * 2 + 1];
  float v[16];
#pragma unroll
  for (int i = 0; i < 8; ++i) v[i] = bf2f(u0[i]);
#pragma unroll
  for (int i = 0; i < 8; ++i) v[8 + i] = bf2f(u1[i]);

  float m = -1e30f;
#pragma unroll
  for (int i = 0; i < 16; ++i) m = fmaxf(m, v[i]);
#pragma unroll
  for (int off = 32; off; off >>= 1) m = fmaxf(m, __shfl_xor(m, off));
  __shared__ float red[8];
  if ((t & 63) == 0) red[t >> 6] = m;
  __syncthreads();
  m = fmaxf(fmaxf(red[0], red[1]), fmaxf(red[2], red[3]));

  float s = 0.f;
#pragma unroll
  for (int i = 0; i < 16; ++i) { v[i] = __expf(v[i] - m); s += v[i]; }
#pragma unroll
  for (int off = 32; off; off >>= 1) s += __shfl_xor(s, off);
  if ((t & 63) == 0) red[4 + (t >> 6)] = s;
  __syncthreads();
  s = (red[4] + red[5]) + (red[6] + red[7]);
  const float inv = 1.0f / s;

  u16x8 o0, o1;
#pragma unroll
  for (int i = 0; i < 8; ++i) o0[i] = f2bf(v[i] * inv);
#pragma unroll
  for (int i = 0; i < 8; ++i) o1[i] = f2bf(v[8 + i] * inv);
  ((u16x8*)p)[t * 2] = o0;
  ((u16x8*)p)[t * 2 + 1] = o1;
}

// -------------------------------------------------------------------------
// S=4096, D_IN=1024, D_OUT=1024.  fp32 in, fp32 out.
// ws (bytes): Ebf 0-8M | Wt 8-14M | QKV 14-38M | Vt 38-46M | S 46-78M |
// P4 (bf16 partials, 32MB) @78M if ws >= 110MB, else aliases dead 0-32M.
// 6 dispatches: prep -> qkv(+tV fused) -> score -> softmax -> pv-splitK
// -> reduce.  GEMMs: 256² 4-phase R8 body (2 barriers/K-tile, vmcnt(4)).
// -------------------------------------------------------------------------
extern "C" void kernel_launch(void* const* d_in, const int* in_sizes, int n_in,
                              void* d_out, int out_size, void* d_ws, size_t ws_size,
                              hipStream_t stream) {
  const float* E  = (const float*)d_in[0];
  const float* Wq = (const float*)d_in[1];
  const float* Wk = (const float*)d_in[2];
  const float* Wv = (const float*)d_in[3];
  float* Out = (float*)d_out;

  char* w = (char*)d_ws;
  u16* Ebf = (u16*)(w);
  u16* Wt  = (u16*)(w + (size_t)(8u << 20));
  u16* QKV = (u16*)(w + (size_t)(14u << 20));
  u16* Vt  = (u16*)(w + (size_t)(38u << 20));
  u16* S   = (u16*)(w + (size_t)(46u << 20));
  u16* P4  = (ws_size >= ((size_t)110u << 20)) ? (u16*)(w + (size_t)(78u << 20))
                                               : (u16*)w;  // dead Ebf/Wt/QKV

  // stage 0: E cast + W transposes
  prep<<<7168, 256, 0, stream>>>(E, Wq, Wk, Wv, Ebf, Wt);

  // stage 1: QKV = E @ Wt^T; V tiles go straight to Vt (transposed)
  gemm_qkv256<<<192, 512, 0, stream>>>(Ebf, Wt, QKV, Vt);

  // stage 2: S = (Q @ K^T) / 32
  gemm_score256<<<256, 512, 0, stream>>>(QKV, S);

  // stage 3: P = softmax(S) in place
  softmax_rows<<<4096, 256, 0, stream>>>(S);

  // stage 4+5: Out = P @ Vt^T via split-K x4 (bf16 partials) + reduce
  gemm_pv256h<<<256, 512, 0, stream>>>(S, Vt, P4);
  reduce4h<<<2048, 256, 0, stream>>>(P4, Out);
}